// Round 1
// baseline (30717.786 us; speedup 1.0000x reference)
//
#include <hip/hip_runtime.h>
#include <hip/hip_cooperative_groups.h>

namespace cg = cooperative_groups;

#define S_LEN 256
#define BATCH 256
#define EDIM 512
#define HDIM 1024
#define NGATE 4
#define KDIM (EDIM + HDIM)   // 1536
#define BK 32
#define NKIT (KDIM / BK)     // 48
#define MT 32                // batch rows per block
#define JT 32                // j columns per block (per gate)
#define NCOL (NGATE * JT)    // 128 output cols per block

typedef short short8 __attribute__((ext_vector_type(8)));
typedef float f32x4 __attribute__((ext_vector_type(4)));

__device__ __forceinline__ unsigned short f2bf(float f) {
  unsigned u = __float_as_uint(f);
  u = u + 0x7FFFu + ((u >> 16) & 1u);   // RNE
  return (unsigned short)(u >> 16);
}
__device__ __forceinline__ float bf2f(unsigned short s) {
  return __uint_as_float(((unsigned)s) << 16);
}
__device__ __forceinline__ float sigf(float x) { return 1.0f / (1.0f + __expf(-x)); }
__device__ __forceinline__ float tanh_(float x) { return 2.0f / (1.0f + __expf(-2.0f * x)) - 1.0f; }

// ---------------- Phase 1: embedding gather -> bf16 X[s][b][e] ----------------
__global__ void gather_embed(const int* __restrict__ inputs, const float* __restrict__ emb,
                             unsigned short* __restrict__ Xbf) {
  int t = blockIdx.x * 256 + threadIdx.x;   // S*B*E/4 = 8,388,608 threads
  int r = t >> 7;                           // row = s*256 + b  (128 thr/row)
  int c = (t & 127) << 2;                   // 4 floats each
  int s = r >> 8, b = r & 255;
  int vid = inputs[b * S_LEN + s];
  float4 v = *(const float4*)(emb + (size_t)vid * EDIM + c);
  unsigned p0 = (unsigned)f2bf(v.x) | ((unsigned)f2bf(v.y) << 16);
  unsigned p1 = (unsigned)f2bf(v.z) | ((unsigned)f2bf(v.w) << 16);
  uint2 pv; pv.x = p0; pv.y = p1;
  *(uint2*)(Xbf + (size_t)r * EDIM + c) = pv;
}

// ---- Phase 2: pack [Wx;Wh] -> bf16 fragment-major WTf[dir][jb][kit][r][kk] ----
// row r (0..127) of a block tile -> global n = (r>>5)*1024 + jb*32 + (r&31)
__global__ void pack_weights(const float* __restrict__ Wx_f, const float* __restrict__ Wh_f,
                             const float* __restrict__ Wx_b, const float* __restrict__ Wh_b,
                             unsigned short* __restrict__ WTf) {
  size_t t = (size_t)blockIdx.x * 256 + threadIdx.x;  // 3,145,728 threads, 4 elems each
  int kk4 = (int)(t & 7) * 4;
  int r   = (int)(t >> 3) & 127;
  int rem = (int)(t >> 10);        // dir*32*48 + jb*48 + kit  (0..3071)
  int kit = rem % 48;
  int jbd = rem / 48;              // 0..63
  int jb  = jbd & 31;
  int dir = jbd >> 5;
  int n = (r >> 5) * 1024 + jb * 32 + (r & 31);
  const float* Wx = dir ? Wx_b : Wx_f;
  const float* Wh = dir ? Wh_b : Wh_f;
  unsigned short o[4];
#pragma unroll
  for (int q = 0; q < 4; ++q) {
    int k = kit * 32 + kk4 + q;
    float v = (k < EDIM) ? Wx[(size_t)k * 4096 + n] : Wh[(size_t)(k - EDIM) * 4096 + n];
    o[q] = f2bf(v);
  }
  unsigned p0 = (unsigned)o[0] | ((unsigned)o[1] << 16);
  unsigned p1 = (unsigned)o[2] | ((unsigned)o[3] << 16);
  uint2 pv; pv.x = p0; pv.y = p1;
  *(uint2*)(WTf + t * 4) = pv;     // dest is exactly linear: coalesced
}

// ---------------- Phase 3: persistent cooperative BiLSTM ----------------
// grid = 512 blocks x 256 thr. Block tile: 32 batch rows x (4 gates x 32 j).
// XCD swizzle: blocks sharing a weight slice (same dir,jb) land on one XCD.
__global__ __launch_bounds__(256, 2) void lstm_main(
    const unsigned short* __restrict__ Xbf,   // [S][B][E]
    const unsigned short* __restrict__ WTf,   // [dir][jb][kit][128][32]
    const float* __restrict__ bias_f,
    const float* __restrict__ bias_b,
    unsigned short* __restrict__ Hbf)         // [2 buf][2 dir][B][H]
{
  __shared__ __align__(16) unsigned short Alds[MT * 40];    // 32 x 32, padded rows
  __shared__ __align__(16) unsigned short Blds[NCOL * 40];  // 128 x 32, padded rows
  __shared__ __align__(16) float gbuf[NGATE][MT][JT];
  __shared__ float biaslds[NCOL];

  const int bx  = blockIdx.x;
  const int xcd = bx & 7;
  const int t2  = bx >> 3;
  const int m0i = t2 & 7;
  const int dj  = (t2 >> 3) * 8 + xcd;   // 0..63
  const int dir = dj >> 5;
  const int jb  = dj & 31;
  const int m0  = m0i * MT;
  const int j0  = jb * JT;

  const int tid  = threadIdx.x;
  const int wave = tid >> 6;       // wave w owns gate w (cols [32w,32w+32))
  const int lane = tid & 63;
  const int lr   = lane & 15;
  const int kq   = (lane >> 4) * 8;

  if (tid < NCOL) {
    const float* bias = dir ? bias_b : bias_f;
    biaslds[tid] = bias[(tid >> 5) * HDIM + j0 + (tid & 31)];
  }

  const unsigned short* wt_block = WTf + (size_t)(dir * 32 + jb) * (NKIT * NCOL * BK);

  // A tile staging: 1024 shorts / 256 thr = 4 each
  const int ar = tid >> 3;
  const int ac = (tid & 7) * 4;
  // B tile staging: 4096 shorts / 256 thr = 16 each (2x uint4)
  const int br = tid >> 1;
  const int bkk = (tid & 1) * 16;

  const size_t xrow = (size_t)(m0 + ar) * EDIM + ac;
  const size_t hrow = (size_t)(dir * BATCH + m0 + ar) * HDIM + ac;

  float c_reg[4] = {0.f, 0.f, 0.f, 0.f};

  cg::grid_group grid = cg::this_grid();

  for (int s = 0; s < S_LEN; ++s) {
    const int sx = dir ? (S_LEN - 1 - s) : s;
    const int rb = s & 1;   // read h buffer; write rb^1
    const unsigned short* __restrict__ xs = Xbf + (size_t)sx * (BATCH * EDIM);
    const unsigned short* __restrict__ hs = Hbf + (size_t)rb * (2 * BATCH * HDIM);

    f32x4 acc00 = {0.f,0.f,0.f,0.f}, acc01 = {0.f,0.f,0.f,0.f};
    f32x4 acc10 = {0.f,0.f,0.f,0.f}, acc11 = {0.f,0.f,0.f,0.f};

    const unsigned short* bsrc = wt_block + br * BK + bkk;

    for (int kit = 0; kit < NKIT; ++kit) {
      const int k0 = kit * BK;
      uint2 av;
      if (k0 < EDIM) av = *(const uint2*)(xs + xrow + k0);
      else           av = *(const uint2*)(hs + hrow + (k0 - EDIM));
      uint4 bv0 = *(const uint4*)(bsrc);
      uint4 bv1 = *(const uint4*)(bsrc + 8);
      bsrc += NCOL * BK;

      __syncthreads();   // protect prev iter's fragment reads
      *(uint2*)(Alds + ar * 40 + ac) = av;
      *(uint4*)(Blds + br * 40 + bkk) = bv0;
      *(uint4*)(Blds + br * 40 + bkk + 8) = bv1;
      __syncthreads();

      short8 a0 = *(const short8*)(Alds + lr * 40 + kq);
      short8 a1 = *(const short8*)(Alds + (16 + lr) * 40 + kq);
      const int cb = wave * 32;
      short8 b0 = *(const short8*)(Blds + (cb + lr) * 40 + kq);
      short8 b1 = *(const short8*)(Blds + (cb + 16 + lr) * 40 + kq);

      acc00 = __builtin_amdgcn_mfma_f32_16x16x32_bf16(a0, b0, acc00, 0, 0, 0);
      acc01 = __builtin_amdgcn_mfma_f32_16x16x32_bf16(a0, b1, acc01, 0, 0, 0);
      acc10 = __builtin_amdgcn_mfma_f32_16x16x32_bf16(a1, b0, acc10, 0, 0, 0);
      acc11 = __builtin_amdgcn_mfma_f32_16x16x32_bf16(a1, b1, acc11, 0, 0, 0);
    }

    // C/D layout (verified m89/m91): col = lane&15, row = (lane>>4)*4 + reg
    {
      const int rq = (lane >> 4) * 4;
#pragma unroll
      for (int r = 0; r < 4; ++r) {
        gbuf[wave][rq + r][lr]           = acc00[r] + biaslds[wave * 32 + lr];
        gbuf[wave][rq + r][16 + lr]      = acc01[r] + biaslds[wave * 32 + 16 + lr];
        gbuf[wave][16 + rq + r][lr]      = acc10[r] + biaslds[wave * 32 + lr];
        gbuf[wave][16 + rq + r][16 + lr] = acc11[r] + biaslds[wave * 32 + 16 + lr];
      }
    }
    __syncthreads();

    // gate combine: thread owns (m = tid>>3, jj = (tid&7)*4 + q); c stays in regs
    {
      const int m = tid >> 3;
      const int jjb = (tid & 7) * 4;
      const int wbuf = rb ^ 1;
      unsigned short* hd = Hbf + (size_t)wbuf * (2 * BATCH * HDIM)
                         + (size_t)(dir * BATCH + m0 + m) * HDIM + j0 + jjb;
#pragma unroll
      for (int q = 0; q < 4; ++q) {
        const int jj = jjb + q;
        float gi = gbuf[0][m][jj];
        float gf = gbuf[1][m][jj];
        float go = gbuf[2][m][jj];
        float gc = gbuf[3][m][jj];
        float cn = sigf(gf) * c_reg[q] + sigf(gi) * tanh_(gc);
        float hn = sigf(go) * tanh_(cn);
        c_reg[q] = cn;
        hd[q] = f2bf(hn);
      }
    }
    __threadfence();   // device-scope visibility across XCDs
    grid.sync();
  }
}

// ---------------- Phase 4: logits + softmax ----------------
__global__ void final_softmax(const unsigned short* __restrict__ Hbf,  // buf0 base
                              const float* __restrict__ Whq,
                              const float* __restrict__ bq,
                              float* __restrict__ out) {
  __shared__ float wl[HDIM * 10];
  const int tid = threadIdx.x;
  for (int i = tid; i < HDIM * 10; i += 256) wl[i] = Whq[i];
  __syncthreads();
  const unsigned short* hf = Hbf + (size_t)tid * HDIM;            // dir0
  const unsigned short* hb = Hbf + (size_t)(BATCH + tid) * HDIM;  // dir1
  float acc[10];
#pragma unroll
  for (int q = 0; q < 10; ++q) acc[q] = bq[q];
  for (int h = 0; h < HDIM; ++h) {
    float xv = bf2f(hf[h]) + bf2f(hb[h]);
#pragma unroll
    for (int q = 0; q < 10; ++q) acc[q] += xv * wl[h * 10 + q];
  }
  float mx = acc[0];
#pragma unroll
  for (int q = 1; q < 10; ++q) mx = fmaxf(mx, acc[q]);
  float sum = 0.f;
#pragma unroll
  for (int q = 0; q < 10; ++q) { acc[q] = __expf(acc[q] - mx); sum += acc[q]; }
  float inv = 1.0f / sum;
#pragma unroll
  for (int q = 0; q < 10; ++q) out[tid * 10 + q] = acc[q] * inv;
}

extern "C" void kernel_launch(void* const* d_in, const int* in_sizes, int n_in,
                              void* d_out, int out_size, void* d_ws, size_t ws_size,
                              hipStream_t stream) {
  const int*   inputs = (const int*)d_in[0];
  const float* emb    = (const float*)d_in[1];
  const float* Wx_f   = (const float*)d_in[2];
  const float* Wh_f   = (const float*)d_in[3];
  const float* b_f    = (const float*)d_in[4];
  const float* Wx_b   = (const float*)d_in[5];
  const float* Wh_b   = (const float*)d_in[6];
  const float* b_b    = (const float*)d_in[7];
  const float* W_hq   = (const float*)d_in[8];
  const float* b_q    = (const float*)d_in[9];
  float* out = (float*)d_out;

  char* ws = (char*)d_ws;
  unsigned short* Xbf = (unsigned short*)ws;                         // 64 MiB: [S][B][E]
  unsigned short* WTf = (unsigned short*)(ws + ((size_t)64 << 20));  // 24 MiB: packed weights
  unsigned short* Hbf = (unsigned short*)(ws + ((size_t)96 << 20));  // 2 MiB: h ping-pong

  // zero h buffer 0 (initial hidden state); ws is poisoned 0xAA each call
  hipMemsetAsync(Hbf, 0, (size_t)2 * BATCH * HDIM * sizeof(unsigned short), stream);

  gather_embed<<<32768, 256, 0, stream>>>(inputs, emb, Xbf);
  pack_weights<<<12288, 256, 0, stream>>>(Wx_f, Wh_f, Wx_b, Wh_b, WTf);

  const unsigned short* xbf_p = Xbf;
  const unsigned short* wtf_p = WTf;
  const float* bf_p = b_f;
  const float* bb_p = b_b;
  unsigned short* hbf_p = Hbf;
  void* kargs[] = { (void*)&xbf_p, (void*)&wtf_p, (void*)&bf_p, (void*)&bb_p, (void*)&hbf_p };
  hipLaunchCooperativeKernel((void*)lstm_main, dim3(512), dim3(256), kargs, 0, stream);

  // after s=255 the final h lives in buffer 0
  final_softmax<<<1, 256, 0, stream>>>(Hbf, W_hq, b_q, out);
}

// Round 2
// 14813.567 us; speedup vs baseline: 2.0736x; 2.0736x over previous
//
#include <hip/hip_runtime.h>

#define S_LEN 256
#define BATCH 256
#define EDIM 512
#define HDIM 1024

typedef short short8 __attribute__((ext_vector_type(8)));
typedef float f32x4 __attribute__((ext_vector_type(4)));

__device__ __forceinline__ unsigned short f2bf(float f) {
  unsigned u = __float_as_uint(f);
  u = u + 0x7FFFu + ((u >> 16) & 1u);   // RNE
  return (unsigned short)(u >> 16);
}
__device__ __forceinline__ float bf2f(unsigned short s) {
  return __uint_as_float(((unsigned)s) << 16);
}
__device__ __forceinline__ float sigf(float x) { return 1.0f / (1.0f + __expf(-x)); }
__device__ __forceinline__ float tanh_(float x) { return 2.0f / (1.0f + __expf(-2.0f * x)) - 1.0f; }

#define MFMA(d, a, b) d = __builtin_amdgcn_mfma_f32_16x16x32_bf16(a, b, d, 0, 0, 0)

// ---------------- Phase 1: embedding gather -> frag-layout Xf[s][kt16][b256][32] bf16 ----------------
// thread T = (s*16 + kt)*256 + b: reads emb[vid][kt*32..+32], writes 64B contiguous at Xf + T*32.
__global__ void gather_embed(const int* __restrict__ inputs, const float* __restrict__ emb,
                             unsigned short* __restrict__ Xf) {
  int T = blockIdx.x * 256 + threadIdx.x;   // 1,048,576 threads
  int b  = T & 255;
  int kt = (T >> 8) & 15;
  int s  = T >> 12;
  int vid = inputs[b * S_LEN + s];
  const float* src = emb + (size_t)vid * EDIM + kt * 32;
  unsigned short o[32];
#pragma unroll
  for (int i = 0; i < 32; i += 4) {
    float4 v = *(const float4*)(src + i);
    o[i] = f2bf(v.x); o[i + 1] = f2bf(v.y); o[i + 2] = f2bf(v.z); o[i + 3] = f2bf(v.w);
  }
  uint4* dst = (uint4*)(Xf + (size_t)T * 32);
#pragma unroll
  for (int q = 0; q < 4; ++q) dst[q] = ((const uint4*)o)[q];
}

// ---------------- Phase 2: pack Wx/Wh into B-frag-native bf16 layout ----------------
// frag unit (dir, jb, kit, nt) = 512 shorts; element (c,q,e) at c*32 + q*8 + e,
// so a wave load with lane ofs (l&15)*64B + (l>>4)*16B is 1 KiB contiguous.
// global n = nt*1024 + jb*16 + c ; k = kit*32 + q*8 + e.
__global__ void pack_w(const float* __restrict__ Wx_f, const float* __restrict__ Wh_f,
                       const float* __restrict__ Wx_b, const float* __restrict__ Wh_b,
                       unsigned short* __restrict__ Wxp, unsigned short* __restrict__ Whp) {
  __shared__ unsigned short tile[32][68];
  int bid = blockIdx.x;                 // 2*64*48 = 6144 blocks
  int kit = bid % 48;
  int jb  = (bid / 48) & 63;
  int dir = bid / (48 * 64);
  const float* W; int kbase;
  if (kit < 16) { W = dir ? Wx_b : Wx_f; kbase = kit * 32; }
  else          { W = dir ? Wh_b : Wh_f; kbase = (kit - 16) * 32; }
  int t = threadIdx.x;
#pragma unroll
  for (int half = 0; half < 2; ++half) {
    int idx = half * 256 + t;           // 512 float4 loads: 32 rows x 16
    int row = idx >> 4;
    int c4  = (idx & 15) << 2;
    int nt  = c4 >> 4;
    int cc  = c4 & 15;
    int n   = nt * 1024 + jb * 16 + cc;
    float4 v = *(const float4*)(W + (size_t)(kbase + row) * 4096 + n);
    tile[row][c4]     = f2bf(v.x); tile[row][c4 + 1] = f2bf(v.y);
    tile[row][c4 + 2] = f2bf(v.z); tile[row][c4 + 3] = f2bf(v.w);
  }
  __syncthreads();
  int nt = t >> 6, cc = (t >> 2) & 15, q = t & 3;
  unsigned short o[8];
#pragma unroll
  for (int e = 0; e < 8; ++e) o[e] = tile[q * 8 + e][nt * 16 + cc];
  size_t unit; unsigned short* dstbase;
  if (kit < 16) { unit = ((size_t)(dir * 64 + jb) * 16 + kit) * 4 + nt;        dstbase = Wxp; }
  else          { unit = ((size_t)(dir * 64 + jb) * 32 + (kit - 16)) * 4 + nt; dstbase = Whp; }
  *(uint4*)(dstbase + unit * 512 + cc * 32 + q * 8) = *(const uint4*)o;
}

// ---------------- Phase 3: persistent BiLSTM, Wh in LDS, group barriers ----------------
// 256 blocks x 256 thr, 1 block/CU (128 KiB dyn LDS). Block = (dir, mh, jb):
//   rows mh*128..+128, cols j = jb*16..+16 per gate (4 gates in-lane -> register gate combine).
// Sync group = (dir, mh): 64 blocks, closed under the h exchange; mapped to 2 XCDs via bx&7.
__global__ __launch_bounds__(256, 1) void lstm_main(
    const unsigned short* __restrict__ Xf,    // [s][kt16][b][32]
    const unsigned short* __restrict__ Wxp,   // frag units
    const unsigned short* __restrict__ Whp,   // frag units
    const float* __restrict__ bias_f,
    const float* __restrict__ bias_b,
    unsigned short* __restrict__ Hf,          // [buf2][dir2][kt32][b256][32]
    unsigned int* __restrict__ barrier_cnt)
{
  extern __shared__ __align__(16) unsigned char smem[];   // 131072 B: Wh B-frags, XOR-swizzled

  const int bx  = blockIdx.x;
  const int xcd = bx & 7;
  const int dir = xcd >> 2;
  const int mh  = (xcd >> 1) & 1;
  const int jb  = ((xcd & 1) << 5) + (bx >> 3);

  const int tid  = threadIdx.x;
  const int wave = tid >> 6;
  const int lane = tid & 63;
  const int c    = lane & 15;    // A-row / B-col within tile
  const int Q    = lane >> 4;    // k-chunk selector
  const int swc  = (c >> 1) & 3; // bank swizzle key

  // ---- one-time LDS fill: Wh slice (dir, jb) = 8192 uint4 ----
  {
    const uint4* src = (const uint4*)Whp + (size_t)(dir * 64 + jb) * 8192;
    for (int i = tid; i < 8192; i += 256) {
      uint4 v = src[i];
      int row = i >> 2, q = i & 3, cc = row & 15;
      *(uint4*)(smem + row * 64 + ((q ^ ((cc >> 1) & 3)) << 4)) = v;
    }
  }
  const float* bias = dir ? bias_b : bias_f;
  const int j = jb * 16 + c;
  float bg[4];
#pragma unroll
  for (int g = 0; g < 4; ++g) bg[g] = bias[g * HDIM + j];
  __syncthreads();

  unsigned int* cnt = barrier_cnt + (dir * 2 + mh) * 32;   // 128B-separated counters

  const int arow = (mh * 128 + wave * 32 + c) * 32 + Q * 8;       // A lane offset in a kt-tile
  const unsigned short* wx_base = Wxp + ((size_t)(dir * 64 + jb) * 16 * 4) * 512 + c * 32 + Q * 8;

  const int kt_j  = j >> 5;
  const int colin = j & 31;

  float c_reg[2][4] = {{0.f,0.f,0.f,0.f},{0.f,0.f,0.f,0.f}};

  for (int s = 0; s < S_LEN; ++s) {
    const int sx = dir ? (S_LEN - 1 - s) : s;
    const int p  = s & 1;    // read h buf p, write p^1

    f32x4 acc[2][4];
#pragma unroll
    for (int mt = 0; mt < 2; ++mt)
#pragma unroll
      for (int g = 0; g < 4; ++g)
        acc[mt][g] = (f32x4){bg[g], bg[g], bg[g], bg[g]};

    // ---- x part (independent of h -> runs before the barrier wait) ----
    {
      const unsigned short* xa = Xf + (size_t)sx * 16 * 8192 + arow;
#pragma unroll 2
      for (int kx = 0; kx < 16; ++kx) {
        short8 a0 = *(const short8*)(xa + kx * 8192);
        short8 a1 = *(const short8*)(xa + kx * 8192 + 512);
        short8 b0 = *(const short8*)(wx_base + (size_t)(kx * 4 + 0) * 512);
        short8 b1 = *(const short8*)(wx_base + (size_t)(kx * 4 + 1) * 512);
        short8 b2 = *(const short8*)(wx_base + (size_t)(kx * 4 + 2) * 512);
        short8 b3 = *(const short8*)(wx_base + (size_t)(kx * 4 + 3) * 512);
        MFMA(acc[0][0], a0, b0); MFMA(acc[0][1], a0, b1);
        MFMA(acc[0][2], a0, b2); MFMA(acc[0][3], a0, b3);
        MFMA(acc[1][0], a1, b0); MFMA(acc[1][1], a1, b1);
        MFMA(acc[1][2], a1, b2); MFMA(acc[1][3], a1, b3);
      }
    }

    // ---- wait for h_s (producers = own 64-block group) ----
    if (s > 0) {
      if (tid == 0) {
        const unsigned target = (unsigned)(64 * s);
        while (__hip_atomic_load(cnt, __ATOMIC_RELAXED, __HIP_MEMORY_SCOPE_AGENT) < target)
          __builtin_amdgcn_s_sleep(1);
      }
      __syncthreads();
      (void)__hip_atomic_load(cnt, __ATOMIC_RELAXED, __HIP_MEMORY_SCOPE_AGENT);
      __threadfence();   // acquire: invalidate caches before reading fresh h
    }

    // ---- h part: A from global Hf (frag layout), B from LDS (no barriers) ----
    {
      const unsigned short* ha = Hf + ((size_t)(p * 2 + dir) * 32) * 8192 + arow;
#pragma unroll 4
      for (int k = 0; k < 32; ++k) {
        short8 a0 = *(const short8*)(ha + (size_t)k * 8192);
        short8 a1 = *(const short8*)(ha + (size_t)k * 8192 + 512);
        const int rb = (k * 4) * 16 + c;
        short8 b0 = *(const short8*)(smem + (size_t)(rb     ) * 64 + ((Q ^ swc) << 4));
        short8 b1 = *(const short8*)(smem + (size_t)(rb + 16) * 64 + ((Q ^ swc) << 4));
        short8 b2 = *(const short8*)(smem + (size_t)(rb + 32) * 64 + ((Q ^ swc) << 4));
        short8 b3 = *(const short8*)(smem + (size_t)(rb + 48) * 64 + ((Q ^ swc) << 4));
        MFMA(acc[0][0], a0, b0); MFMA(acc[0][1], a0, b1);
        MFMA(acc[0][2], a0, b2); MFMA(acc[0][3], a0, b3);
        MFMA(acc[1][0], a1, b0); MFMA(acc[1][1], a1, b1);
        MFMA(acc[1][2], a1, b2); MFMA(acc[1][3], a1, b3);
      }
    }

    // ---- gate combine in registers, write h_{s+1} (frag layout) ----
    {
      unsigned short* hd = Hf + (((size_t)((p ^ 1) * 2 + dir) * 32) + kt_j) * 8192 + colin;
#pragma unroll
      for (int mt = 0; mt < 2; ++mt) {
        const int mrow = mh * 128 + wave * 32 + mt * 16 + Q * 4;
#pragma unroll
        for (int r = 0; r < 4; ++r) {
          float gi = acc[mt][0][r], gf = acc[mt][1][r];
          float go = acc[mt][2][r], gc = acc[mt][3][r];
          float cn = sigf(gf) * c_reg[mt][r] + sigf(gi) * tanh_(gc);
          c_reg[mt][r] = cn;
          hd[(size_t)(mrow + r) * 32] = f2bf(sigf(go) * tanh_(cn));
        }
      }
    }
    __threadfence();     // release h stores to agent scope
    __syncthreads();
    if (tid == 0)
      __hip_atomic_fetch_add(cnt, 1u, __ATOMIC_RELAXED, __HIP_MEMORY_SCOPE_AGENT);
  }
}

// ---------------- Phase 4: logits + softmax ----------------
__global__ void final_softmax(const unsigned short* __restrict__ Hf,  // buf0
                              const float* __restrict__ Whq,
                              const float* __restrict__ bq,
                              float* __restrict__ out) {
  __shared__ float wl[HDIM * 10];
  const int tid = threadIdx.x;
  for (int i = tid; i < HDIM * 10; i += 256) wl[i] = Whq[i];
  __syncthreads();
  float acc[10];
#pragma unroll
  for (int q = 0; q < 10; ++q) acc[q] = bq[q];
  for (int jj = 0; jj < HDIM; ++jj) {
    int kt = jj >> 5, col = jj & 31;
    float xv = bf2f(Hf[(size_t)kt * 8192 + tid * 32 + col])          // dir0
             + bf2f(Hf[(size_t)(32 + kt) * 8192 + tid * 32 + col]);  // dir1
#pragma unroll
    for (int q = 0; q < 10; ++q) acc[q] += xv * wl[jj * 10 + q];
  }
  float mx = acc[0];
#pragma unroll
  for (int q = 1; q < 10; ++q) mx = fmaxf(mx, acc[q]);
  float sum = 0.f;
#pragma unroll
  for (int q = 0; q < 10; ++q) { acc[q] = __expf(acc[q] - mx); sum += acc[q]; }
  float inv = 1.0f / sum;
#pragma unroll
  for (int q = 0; q < 10; ++q) out[tid * 10 + q] = acc[q] * inv;
}

extern "C" void kernel_launch(void* const* d_in, const int* in_sizes, int n_in,
                              void* d_out, int out_size, void* d_ws, size_t ws_size,
                              hipStream_t stream) {
  const int*   inputs = (const int*)d_in[0];
  const float* emb    = (const float*)d_in[1];
  const float* Wx_f   = (const float*)d_in[2];
  const float* Wh_f   = (const float*)d_in[3];
  const float* b_f    = (const float*)d_in[4];
  const float* Wx_b   = (const float*)d_in[5];
  const float* Wh_b   = (const float*)d_in[6];
  const float* b_b    = (const float*)d_in[7];
  const float* W_hq   = (const float*)d_in[8];
  const float* b_q    = (const float*)d_in[9];
  float* out = (float*)d_out;

  char* ws = (char*)d_ws;
  unsigned short* Xf  = (unsigned short*)ws;                     // 64 MiB
  unsigned short* Wxp = (unsigned short*)(ws + (64ull << 20));   //  8 MiB
  unsigned short* Whp = (unsigned short*)(ws + (72ull << 20));   // 16 MiB
  unsigned short* Hf  = (unsigned short*)(ws + (88ull << 20));   //  2 MiB (2 bufs)
  unsigned int*   cnt = (unsigned int*)(ws + (90ull << 20));     // 512 B

  // zero h buffer 0 (initial state) + barrier counters; ws is re-poisoned each call
  hipMemsetAsync(Hf, 0, (size_t)2 * 32 * 8192 * 2, stream);
  hipMemsetAsync(cnt, 0, 512, stream);

  gather_embed<<<4096, 256, 0, stream>>>(inputs, emb, Xf);
  pack_w<<<6144, 256, 0, stream>>>(Wx_f, Wh_f, Wx_b, Wh_b, Wxp, Whp);

  hipFuncSetAttribute((const void*)lstm_main,
                      hipFuncAttributeMaxDynamicSharedMemorySize, 131072);

  const unsigned short* xf_p = Xf;
  const unsigned short* wxp_p = Wxp;
  const unsigned short* whp_p = Whp;
  const float* bf_p = b_f;
  const float* bb_p = b_b;
  unsigned short* hf_p = Hf;
  unsigned int* cnt_p = cnt;
  void* kargs[] = { (void*)&xf_p, (void*)&wxp_p, (void*)&whp_p, (void*)&bf_p,
                    (void*)&bb_p, (void*)&hf_p, (void*)&cnt_p };
  hipLaunchCooperativeKernel((void*)lstm_main, dim3(256), dim3(256), kargs, 131072, stream);

  // final h (step 256) lives in buf 0
  final_softmax<<<1, 256, 0, stream>>>(Hf, W_hq, b_q, out);
}

// Round 3
// 5132.478 us; speedup vs baseline: 5.9850x; 2.8862x over previous
//
#include <hip/hip_runtime.h>

#define S_LEN 256
#define BATCH 256
#define EDIM 512
#define HDIM 1024

typedef short short8 __attribute__((ext_vector_type(8)));
typedef float f32x4 __attribute__((ext_vector_type(4)));
typedef unsigned long long u64;

__device__ __forceinline__ unsigned short f2bf(float f) {
  unsigned u = __float_as_uint(f);
  u = u + 0x7FFFu + ((u >> 16) & 1u);   // RNE
  return (unsigned short)(u >> 16);
}
__device__ __forceinline__ float bf2f(unsigned short s) {
  return __uint_as_float(((unsigned)s) << 16);
}
__device__ __forceinline__ float sigf(float x) { return 1.0f / (1.0f + __expf(-x)); }
__device__ __forceinline__ float tanh_(float x) { return 2.0f / (1.0f + __expf(-2.0f * x)) - 1.0f; }

#define MFMA(d, a, b) d = __builtin_amdgcn_mfma_f32_16x16x32_bf16(a, b, d, 0, 0, 0)

// Coherent (L3) 16B h-frag load: two 8B agent-scope relaxed atomic loads.
// Emits global_load_dwordx2 sc0 sc1 — bypasses stale L1/L2, no buffer_inv needed.
__device__ __forceinline__ short8 load_hfrag(const unsigned short* p) {
  union { u64 d[2]; short8 v; } u;
  u.d[0] = __hip_atomic_load((const u64*)p,       __ATOMIC_RELAXED, __HIP_MEMORY_SCOPE_AGENT);
  u.d[1] = __hip_atomic_load((const u64*)(p + 4), __ATOMIC_RELAXED, __HIP_MEMORY_SCOPE_AGENT);
  return u.v;
}

// ---------------- Phase 1: embedding gather -> frag-layout Xf[s][kt16][b256][32] bf16 ----------------
__global__ void gather_embed(const int* __restrict__ inputs, const float* __restrict__ emb,
                             unsigned short* __restrict__ Xf) {
  int T = blockIdx.x * 256 + threadIdx.x;   // 1,048,576 threads
  int b  = T & 255;
  int kt = (T >> 8) & 15;
  int s  = T >> 12;
  int vid = inputs[b * S_LEN + s];
  const float* src = emb + (size_t)vid * EDIM + kt * 32;
  unsigned short o[32];
#pragma unroll
  for (int i = 0; i < 32; i += 4) {
    float4 v = *(const float4*)(src + i);
    o[i] = f2bf(v.x); o[i + 1] = f2bf(v.y); o[i + 2] = f2bf(v.z); o[i + 3] = f2bf(v.w);
  }
  uint4* dst = (uint4*)(Xf + (size_t)T * 32);
#pragma unroll
  for (int q = 0; q < 4; ++q) dst[q] = ((const uint4*)o)[q];
}

// ---------------- Phase 2: pack Wx/Wh into B-frag-native bf16 layout ----------------
__global__ void pack_w(const float* __restrict__ Wx_f, const float* __restrict__ Wh_f,
                       const float* __restrict__ Wx_b, const float* __restrict__ Wh_b,
                       unsigned short* __restrict__ Wxp, unsigned short* __restrict__ Whp) {
  __shared__ unsigned short tile[32][68];
  int bid = blockIdx.x;                 // 2*64*48 = 6144 blocks
  int kit = bid % 48;
  int jb  = (bid / 48) & 63;
  int dir = bid / (48 * 64);
  const float* W; int kbase;
  if (kit < 16) { W = dir ? Wx_b : Wx_f; kbase = kit * 32; }
  else          { W = dir ? Wh_b : Wh_f; kbase = (kit - 16) * 32; }
  int t = threadIdx.x;
#pragma unroll
  for (int half = 0; half < 2; ++half) {
    int idx = half * 256 + t;           // 512 float4 loads: 32 rows x 16
    int row = idx >> 4;
    int c4  = (idx & 15) << 2;
    int nt  = c4 >> 4;
    int cc  = c4 & 15;
    int n   = nt * 1024 + jb * 16 + cc;
    float4 v = *(const float4*)(W + (size_t)(kbase + row) * 4096 + n);
    tile[row][c4]     = f2bf(v.x); tile[row][c4 + 1] = f2bf(v.y);
    tile[row][c4 + 2] = f2bf(v.z); tile[row][c4 + 3] = f2bf(v.w);
  }
  __syncthreads();
  int nt = t >> 6, cc = (t >> 2) & 15, q = t & 3;
  unsigned short o[8];
#pragma unroll
  for (int e = 0; e < 8; ++e) o[e] = tile[q * 8 + e][nt * 16 + cc];
  size_t unit; unsigned short* dstbase;
  if (kit < 16) { unit = ((size_t)(dir * 64 + jb) * 16 + kit) * 4 + nt;        dstbase = Wxp; }
  else          { unit = ((size_t)(dir * 64 + jb) * 32 + (kit - 16)) * 4 + nt; dstbase = Whp; }
  *(uint4*)(dstbase + unit * 512 + cc * 32 + q * 8) = *(const uint4*)o;
}

// ---------------- Phase 3: persistent BiLSTM, Wh in LDS, slot-based sync, NO cache fences ----------------
__global__ __launch_bounds__(256, 1) void lstm_main(
    const unsigned short* __restrict__ Xf,    // [s][kt16][b][32]
    const unsigned short* __restrict__ Wxp,   // frag units
    const unsigned short* __restrict__ Whp,   // frag units
    const float* __restrict__ bias_f,
    const float* __restrict__ bias_b,
    unsigned short* __restrict__ Hf,          // [buf2][dir2][kt32][b256][32]
    unsigned int* __restrict__ slots)         // [group4][64 blocks][16 u32 pad]
{
  extern __shared__ __align__(16) unsigned char smem[];   // 131072 B: Wh B-frags, XOR-swizzled

  const int bx  = blockIdx.x;
  const int xcd = bx & 7;
  const int dir = xcd >> 2;
  const int mh  = (xcd >> 1) & 1;
  const int jb  = ((xcd & 1) << 5) + (bx >> 3);

  const int tid  = threadIdx.x;
  const int wave = tid >> 6;
  const int lane = tid & 63;
  const int c    = lane & 15;    // A-row / B-col within tile
  const int Q    = lane >> 4;    // k-chunk selector
  const int swc  = (c >> 1) & 3; // bank swizzle key

  // ---- one-time LDS fill: Wh slice (dir, jb) = 8192 uint4 ----
  {
    const uint4* src = (const uint4*)Whp + (size_t)(dir * 64 + jb) * 8192;
    for (int i = tid; i < 8192; i += 256) {
      uint4 v = src[i];
      int row = i >> 2, q = i & 3, cc = row & 15;
      *(uint4*)(smem + row * 64 + ((q ^ ((cc >> 1) & 3)) << 4)) = v;
    }
  }
  const float* bias = dir ? bias_b : bias_f;
  const int j = jb * 16 + c;
  float bg[4];
#pragma unroll
  for (int g = 0; g < 4; ++g) bg[g] = bias[g * HDIM + j];
  __syncthreads();

  unsigned int* grp_slots = slots + (dir * 2 + mh) * (64 * 16);
  unsigned int* my_slot   = grp_slots + jb * 16;

  const int arow = (mh * 128 + wave * 32 + c) * 32 + Q * 8;
  const unsigned short* wx_base = Wxp + ((size_t)(dir * 64 + jb) * 16 * 4) * 512 + c * 32 + Q * 8;

  const int kt_j  = j >> 5;
  const int colin = j & 31;

  float c_reg[2][4] = {{0.f,0.f,0.f,0.f},{0.f,0.f,0.f,0.f}};

  for (int s = 0; s < S_LEN; ++s) {
    const int sx = dir ? (S_LEN - 1 - s) : s;
    const int p  = s & 1;    // read h buf p, write p^1

    f32x4 acc[2][4];
#pragma unroll
    for (int mt = 0; mt < 2; ++mt)
#pragma unroll
      for (int g = 0; g < 4; ++g)
        acc[mt][g] = (f32x4){bg[g], bg[g], bg[g], bg[g]};

    // ---- x part (independent of h -> runs before the slot wait) ----
    {
      const unsigned short* xa = Xf + (size_t)sx * 16 * 8192 + arow;
#pragma unroll 4
      for (int kx = 0; kx < 16; ++kx) {
        short8 a0 = *(const short8*)(xa + kx * 8192);
        short8 a1 = *(const short8*)(xa + kx * 8192 + 512);
        short8 b0 = *(const short8*)(wx_base + (size_t)(kx * 4 + 0) * 512);
        short8 b1 = *(const short8*)(wx_base + (size_t)(kx * 4 + 1) * 512);
        short8 b2 = *(const short8*)(wx_base + (size_t)(kx * 4 + 2) * 512);
        short8 b3 = *(const short8*)(wx_base + (size_t)(kx * 4 + 3) * 512);
        MFMA(acc[0][0], a0, b0); MFMA(acc[0][1], a0, b1);
        MFMA(acc[0][2], a0, b2); MFMA(acc[0][3], a0, b3);
        MFMA(acc[1][0], a1, b0); MFMA(acc[1][1], a1, b1);
        MFMA(acc[1][2], a1, b2); MFMA(acc[1][3], a1, b3);
      }
    }

    // ---- wait for h_s: wave0 polls all 64 producer slots, one per lane ----
    if (s > 0) {
      if (tid < 64) {
        const unsigned int* sl = grp_slots + tid * 16;
        for (;;) {
          unsigned v = __hip_atomic_load(sl, __ATOMIC_RELAXED, __HIP_MEMORY_SCOPE_AGENT);
          if (!__any(v < (unsigned)s)) break;
          __builtin_amdgcn_s_sleep(1);
        }
      }
      __syncthreads();
      asm volatile("" ::: "memory");
    }

    // ---- h part: A from L3 (coherent frag loads, prefetch depth 4), B from LDS ----
    {
      const unsigned short* ha = Hf + ((size_t)(p * 2 + dir) * 32) * 8192 + arow;
      short8 pa0[4], pa1[4];
#pragma unroll
      for (int i = 0; i < 4; ++i) {
        pa0[i] = load_hfrag(ha + (size_t)i * 8192);
        pa1[i] = load_hfrag(ha + (size_t)i * 8192 + 512);
      }
#pragma unroll 4
      for (int k = 0; k < 28; ++k) {
        short8 a0 = pa0[k & 3], a1 = pa1[k & 3];
        pa0[k & 3] = load_hfrag(ha + (size_t)(k + 4) * 8192);
        pa1[k & 3] = load_hfrag(ha + (size_t)(k + 4) * 8192 + 512);
        const int rb = (k * 4) * 16 + c;
        short8 b0 = *(const short8*)(smem + (size_t)(rb     ) * 64 + ((Q ^ swc) << 4));
        short8 b1 = *(const short8*)(smem + (size_t)(rb + 16) * 64 + ((Q ^ swc) << 4));
        short8 b2 = *(const short8*)(smem + (size_t)(rb + 32) * 64 + ((Q ^ swc) << 4));
        short8 b3 = *(const short8*)(smem + (size_t)(rb + 48) * 64 + ((Q ^ swc) << 4));
        MFMA(acc[0][0], a0, b0); MFMA(acc[0][1], a0, b1);
        MFMA(acc[0][2], a0, b2); MFMA(acc[0][3], a0, b3);
        MFMA(acc[1][0], a1, b0); MFMA(acc[1][1], a1, b1);
        MFMA(acc[1][2], a1, b2); MFMA(acc[1][3], a1, b3);
      }
#pragma unroll
      for (int k = 28; k < 32; ++k) {
        short8 a0 = pa0[k & 3], a1 = pa1[k & 3];
        const int rb = (k * 4) * 16 + c;
        short8 b0 = *(const short8*)(smem + (size_t)(rb     ) * 64 + ((Q ^ swc) << 4));
        short8 b1 = *(const short8*)(smem + (size_t)(rb + 16) * 64 + ((Q ^ swc) << 4));
        short8 b2 = *(const short8*)(smem + (size_t)(rb + 32) * 64 + ((Q ^ swc) << 4));
        short8 b3 = *(const short8*)(smem + (size_t)(rb + 48) * 64 + ((Q ^ swc) << 4));
        MFMA(acc[0][0], a0, b0); MFMA(acc[0][1], a0, b1);
        MFMA(acc[0][2], a0, b2); MFMA(acc[0][3], a0, b3);
        MFMA(acc[1][0], a1, b0); MFMA(acc[1][1], a1, b1);
        MFMA(acc[1][2], a1, b2); MFMA(acc[1][3], a1, b3);
      }
    }

    // ---- gate combine in registers; write h_{s+1} via coherent (sc0 sc1) stores ----
    {
      unsigned short* hd = Hf + (((size_t)((p ^ 1) * 2 + dir) * 32) + kt_j) * 8192 + colin;
#pragma unroll
      for (int mt = 0; mt < 2; ++mt) {
        const int mrow = mh * 128 + wave * 32 + mt * 16 + Q * 4;
#pragma unroll
        for (int r = 0; r < 4; ++r) {
          float gi = acc[mt][0][r], gf = acc[mt][1][r];
          float go = acc[mt][2][r], gc = acc[mt][3][r];
          float cn = sigf(gf) * c_reg[mt][r] + sigf(gi) * tanh_(gc);
          c_reg[mt][r] = cn;
          __hip_atomic_store(hd + (size_t)(mrow + r) * 32, f2bf(sigf(go) * tanh_(cn)),
                             __ATOMIC_RELAXED, __HIP_MEMORY_SCOPE_AGENT);
        }
      }
    }
    // publish: per-wave drain (sc1 stores ack from coherence point), then slot store (no RMW)
    asm volatile("s_waitcnt vmcnt(0)" ::: "memory");
    __syncthreads();
    if (tid == 0)
      __hip_atomic_store(my_slot, (unsigned)(s + 1), __ATOMIC_RELAXED, __HIP_MEMORY_SCOPE_AGENT);
  }
}

// ---------------- Phase 4: logits + softmax, one block per batch row ----------------
__global__ void final_softmax(const unsigned short* __restrict__ Hf,  // buf0
                              const float* __restrict__ Whq,
                              const float* __restrict__ bq,
                              float* __restrict__ out) {
  __shared__ float red[4][10];
  const int b = blockIdx.x;
  const int tid = threadIdx.x;
  float acc[10];
#pragma unroll
  for (int q = 0; q < 10; ++q) acc[q] = 0.f;
#pragma unroll
  for (int d = 0; d < 2; ++d) {
    const unsigned short* hb = Hf + (size_t)d * 32 * 8192;
#pragma unroll
    for (int u = 0; u < 4; ++u) {
      int jj = tid * 4 + u;
      int kt = jj >> 5, col = jj & 31;
      float xv = bf2f(hb[(size_t)kt * 8192 + b * 32 + col]);
#pragma unroll
      for (int q = 0; q < 10; ++q) acc[q] += xv * Whq[jj * 10 + q];
    }
  }
#pragma unroll
  for (int q = 0; q < 10; ++q)
#pragma unroll
    for (int off = 32; off; off >>= 1) acc[q] += __shfl_down(acc[q], off, 64);
  if ((tid & 63) == 0)
#pragma unroll
    for (int q = 0; q < 10; ++q) red[tid >> 6][q] = acc[q];
  __syncthreads();
  if (tid == 0) {
    float t[10];
#pragma unroll
    for (int q = 0; q < 10; ++q)
      t[q] = red[0][q] + red[1][q] + red[2][q] + red[3][q] + bq[q];
    float mx = t[0];
#pragma unroll
    for (int q = 1; q < 10; ++q) mx = fmaxf(mx, t[q]);
    float sum = 0.f;
#pragma unroll
    for (int q = 0; q < 10; ++q) { t[q] = __expf(t[q] - mx); sum += t[q]; }
    float inv = 1.0f / sum;
#pragma unroll
    for (int q = 0; q < 10; ++q) out[b * 10 + q] = t[q] * inv;
  }
}

extern "C" void kernel_launch(void* const* d_in, const int* in_sizes, int n_in,
                              void* d_out, int out_size, void* d_ws, size_t ws_size,
                              hipStream_t stream) {
  const int*   inputs = (const int*)d_in[0];
  const float* emb    = (const float*)d_in[1];
  const float* Wx_f   = (const float*)d_in[2];
  const float* Wh_f   = (const float*)d_in[3];
  const float* b_f    = (const float*)d_in[4];
  const float* Wx_b   = (const float*)d_in[5];
  const float* Wh_b   = (const float*)d_in[6];
  const float* b_b    = (const float*)d_in[7];
  const float* W_hq   = (const float*)d_in[8];
  const float* b_q    = (const float*)d_in[9];
  float* out = (float*)d_out;

  char* ws = (char*)d_ws;
  unsigned short* Xf  = (unsigned short*)ws;                     // 64 MiB
  unsigned short* Wxp = (unsigned short*)(ws + (64ull << 20));   //  8 MiB
  unsigned short* Whp = (unsigned short*)(ws + (72ull << 20));   // 16 MiB
  unsigned short* Hf  = (unsigned short*)(ws + (88ull << 20));   //  2 MiB (2 bufs)
  unsigned int*   slt = (unsigned int*)(ws + (90ull << 20));     // 16 KiB slots

  hipMemsetAsync(Hf, 0, (size_t)2 * 2 * 32 * 8192 * sizeof(unsigned short), stream);
  hipMemsetAsync(slt, 0, 4 * 64 * 16 * sizeof(unsigned int), stream);

  gather_embed<<<4096, 256, 0, stream>>>(inputs, emb, Xf);
  pack_w<<<6144, 256, 0, stream>>>(Wx_f, Wh_f, Wx_b, Wh_b, Wxp, Whp);

  hipFuncSetAttribute((const void*)lstm_main,
                      hipFuncAttributeMaxDynamicSharedMemorySize, 131072);

  const unsigned short* xf_p = Xf;
  const unsigned short* wxp_p = Wxp;
  const unsigned short* whp_p = Whp;
  const float* bf_p = b_f;
  const float* bb_p = b_b;
  unsigned short* hf_p = Hf;
  unsigned int* slt_p = slt;
  void* kargs[] = { (void*)&xf_p, (void*)&wxp_p, (void*)&whp_p, (void*)&bf_p,
                    (void*)&bb_p, (void*)&hf_p, (void*)&slt_p };
  hipLaunchCooperativeKernel((void*)lstm_main, dim3(256), dim3(256), kargs, 131072, stream);

  // final h (step 256) lives in buf 0
  final_softmax<<<256, 256, 0, stream>>>(Hf, W_hq, b_q, out);
}

// Round 4
// 4565.040 us; speedup vs baseline: 6.7289x; 1.1243x over previous
//
#include <hip/hip_runtime.h>

#define S_LEN 256
#define BATCH 256
#define EDIM 512
#define HDIM 1024
#define LDS_BYTES 131072   // 16 resident Wh k-tiles * 8 KB

typedef short short8 __attribute__((ext_vector_type(8)));
typedef float f32x4 __attribute__((ext_vector_type(4)));
typedef unsigned long long u64;
typedef unsigned short us;

__device__ __forceinline__ us f2bf(float f) {
  unsigned u = __float_as_uint(f);
  u = u + 0x7FFFu + ((u >> 16) & 1u);   // RNE
  return (us)(u >> 16);
}
__device__ __forceinline__ float bf2f(us s) {
  return __uint_as_float(((unsigned)s) << 16);
}
__device__ __forceinline__ float sigf(float x) { return 1.0f / (1.0f + __expf(-x)); }
__device__ __forceinline__ float tanh_(float x) { return 2.0f / (1.0f + __expf(-2.0f * x)) - 1.0f; }

#define MFMA(d, a, b) d = __builtin_amdgcn_mfma_f32_16x16x32_bf16(a, b, d, 0, 0, 0)

// Coherent (L3) 16B frag load: two 8B agent-scope relaxed atomic loads (R3-proven).
__device__ __forceinline__ short8 load_hfrag(const us* p) {
  union { u64 d[2]; short8 v; } u;
  u.d[0] = __hip_atomic_load((const u64*)p,       __ATOMIC_RELAXED, __HIP_MEMORY_SCOPE_AGENT);
  u.d[1] = __hip_atomic_load((const u64*)(p + 4), __ATOMIC_RELAXED, __HIP_MEMORY_SCOPE_AGENT);
  return u.v;
}
__device__ __forceinline__ short8 ldf(const us* p) {  // plain 16B frag load
  union { uint4 d; short8 v; } u;
  u.d = *(const uint4*)p;
  return u.v;
}

// All frag units are LANE-LINEAR: unit = 512 shorts (1 KB); lane l's 16 bytes at l*16.
// A-unit (16 batch rows x 32 k): elem (c=row, q=kchunk, e) at short (c + 16q)*8 + e.
// B-unit (16 n cols  x 32 k): elem (c=col, q, e) at short (c + 16q)*8 + e.

// ---------------- Phase 1: gather -> Xf[s][kt16][btile16][512] ----------------
__global__ void gather_embed(const int* __restrict__ inputs, const float* __restrict__ emb,
                             us* __restrict__ Xf) {
  int T = blockIdx.x * 256 + threadIdx.x;   // 1,048,576
  int kt = T & 15;
  int b  = (T >> 4) & 255;
  int s  = T >> 12;
  int vid = inputs[b * S_LEN + s];
  const float* src = emb + (size_t)vid * EDIM + kt * 32;
  int c = b & 15;
  us* ub = Xf + ((size_t)(s * 16 + kt) * 16 + (b >> 4)) * 512;
#pragma unroll
  for (int q = 0; q < 4; ++q) {
    float4 v0 = *(const float4*)(src + q * 8);
    float4 v1 = *(const float4*)(src + q * 8 + 4);
    us o[8] = { f2bf(v0.x), f2bf(v0.y), f2bf(v0.z), f2bf(v0.w),
                f2bf(v1.x), f2bf(v1.y), f2bf(v1.z), f2bf(v1.w) };
    *(uint4*)(ub + (size_t)(c + 16 * q) * 8) = *(const uint4*)o;
  }
}

// ---------------- Phase 2: pack W into lane-linear frag units ----------------
// Wxp[dir][jb][kit 0..15][t 0..7][512] ; Whp[dir][jb][hk 0..31][t][512]
// t = g*2 + h16 ; global col n = g*1024 + jb*32 + h16*16 + c ; k = kit*32 + q*8 + e.
__global__ void pack_w(const float* __restrict__ Wx_f, const float* __restrict__ Wh_f,
                       const float* __restrict__ Wx_b, const float* __restrict__ Wh_b,
                       us* __restrict__ Wxp, us* __restrict__ Whp) {
  int T = blockIdx.x * 256 + threadIdx.x;   // 1,572,864
  int c = T & 15;
  int q = (T >> 4) & 3;
  int t = (T >> 6) & 7;
  int r = T >> 9;                           // 0..3071
  int kit = r % 48;
  int jbd = r / 48;
  int jb  = jbd & 31;
  int dir = jbd >> 5;
  int g = t >> 1, h16 = t & 1;
  int n = g * 1024 + jb * 32 + h16 * 16 + c;
  const float* W; int k0;
  if (kit < 16) { W = dir ? Wx_b : Wx_f; k0 = kit * 32 + q * 8; }
  else          { W = dir ? Wh_b : Wh_f; k0 = (kit - 16) * 32 + q * 8; }
  us o[8];
#pragma unroll
  for (int e = 0; e < 8; ++e) o[e] = f2bf(W[(size_t)(k0 + e) * 4096 + n]);
  us* dst;
  if (kit < 16) dst = Wxp + (((size_t)(dir * 32 + jb) * 16 + kit) * 8 + t) * 512;
  else          dst = Whp + (((size_t)(dir * 32 + jb) * 32 + (kit - 16)) * 8 + t) * 512;
  *(uint4*)(dst + (size_t)(c + 16 * q) * 8) = *(const uint4*)o;
}

// ---------------- Phase 3: persistent BiLSTM ----------------
// 256 blocks x 256 thr. Block (dir, mq, jb): rows mq*64..+64, cols j = jb*32..+32 per gate.
// Wave (mw, nw) = [32 m x 64 n(4g x 16j)]. Group (dir,mq) = 32 blocks (h-exchange closed).
// XCD swizzle: xcd hint = (dir, jb-octet) -> per-XCD L2 holds 8 jb W-slices (~2 MB).
__global__ __launch_bounds__(256, 1) void lstm_main(
    const us* __restrict__ Xf,
    const us* __restrict__ Wxp,
    const us* __restrict__ Whp,
    const float* __restrict__ bias_f,
    const float* __restrict__ bias_b,
    us* __restrict__ Hf,                    // [buf2][dir2][kt32][btile16][512]
    unsigned int* __restrict__ slots)       // [group8][32][16]
{
  extern __shared__ __align__(16) unsigned char smem[];  // Wh hk 16..31, unit-linear

  const int bx   = blockIdx.x;
  const int xcd  = bx & 7;
  const int dir  = xcd >> 2;
  const int joct = xcd & 3;
  const int rr   = bx >> 3;           // 0..31
  const int jb   = joct * 8 + (rr & 7);
  const int mq   = rr >> 3;

  const int tid  = threadIdx.x;
  const int wave = tid >> 6;
  const int lane = tid & 63;
  const int mw   = wave & 1;
  const int nw   = wave >> 1;
  const int c    = lane & 15;
  const int q    = lane >> 4;
  const int lofs = lane * 8;          // shorts (16 B)

  // one-time LDS fill: Whp units (dir,jb), hk 16..31 -> 8192 uint4, linear
  {
    const uint4* src = (const uint4*)(Whp + (((size_t)(dir * 32 + jb) * 32 + 16) * 8) * 512);
    for (int i = tid; i < 8192; i += 256) *(uint4*)(smem + (size_t)i * 16) = src[i];
  }
  const float* bias = dir ? bias_b : bias_f;
  const int j = jb * 32 + nw * 16 + c;
  float bg[4];
#pragma unroll
  for (int g = 0; g < 4; ++g) bg[g] = bias[g * HDIM + j];
  __syncthreads();

  unsigned int* grp_slots = slots + (dir * 4 + mq) * (32 * 16);
  unsigned int* my_slot   = grp_slots + jb * 16;

  const int bt0 = mq * 4 + mw * 2;
  const us* xu_base  = Xf + (size_t)bt0 * 512 + lofs;
  const us* wxu = Wxp + (((size_t)(dir * 32 + jb) * 16) * 8 + nw) * 512 + lofs;
  const us* whu = Whp + (((size_t)(dir * 32 + jb) * 32) * 8 + nw) * 512 + lofs;
  const int ldsofs = (nw * 512 + lane * 8) * 2;   // + g*2048 + hk*8192 bytes

  float c_reg[2][4] = {{0.f,0.f,0.f,0.f},{0.f,0.f,0.f,0.f}};

  for (int s = 0; s < S_LEN; ++s) {
    const int sx = dir ? (S_LEN - 1 - s) : s;
    const int p  = s & 1;

    f32x4 acc[2][4];
#pragma unroll
    for (int mt = 0; mt < 2; ++mt)
#pragma unroll
      for (int g = 0; g < 4; ++g)
        acc[mt][g] = (f32x4){bg[g], bg[g], bg[g], bg[g]};

    // ---- x-part (no h dependency; runs before the wait) ----
    {
      const us* xu = xu_base + (size_t)sx * (16 * 16 * 512);
#pragma unroll 4
      for (int k = 0; k < 16; ++k) {
        short8 a0 = ldf(xu + (size_t)k * 8192);
        short8 a1 = ldf(xu + (size_t)k * 8192 + 512);
        const us* wb = wxu + (size_t)k * 4096;
        short8 b0 = ldf(wb);
        short8 b1 = ldf(wb + 1024);
        short8 b2 = ldf(wb + 2048);
        short8 b3 = ldf(wb + 3072);
        MFMA(acc[0][0], a0, b0); MFMA(acc[0][1], a0, b1);
        MFMA(acc[0][2], a0, b2); MFMA(acc[0][3], a0, b3);
        MFMA(acc[1][0], a1, b0); MFMA(acc[1][1], a1, b1);
        MFMA(acc[1][2], a1, b2); MFMA(acc[1][3], a1, b3);
      }
    }

    // ---- wait for h_s: lanes 0..31 poll the 32 producer slots of own group ----
    if (s > 0) {
      if (tid < 32) {
        const unsigned int* sl = grp_slots + tid * 16;
        for (;;) {
          unsigned v = __hip_atomic_load(sl, __ATOMIC_RELAXED, __HIP_MEMORY_SCOPE_AGENT);
          if (!__any(v < (unsigned)s)) break;
          __builtin_amdgcn_s_sleep(1);
        }
      }
      __syncthreads();
      asm volatile("" ::: "memory");
    }

    // ---- h-part: A coherent from Hf (prefetch depth 4); B: streamed hk 0..15, LDS hk 16..31 ----
    {
      const us* hu = Hf + (((size_t)(p * 2 + dir) * 32) * 16 + bt0) * 512 + lofs;
      short8 pa0[4], pa1[4];
#pragma unroll
      for (int i = 0; i < 4; ++i) {
        pa0[i] = load_hfrag(hu + (size_t)i * 8192);
        pa1[i] = load_hfrag(hu + (size_t)i * 8192 + 512);
      }
#pragma unroll 4
      for (int k = 0; k < 16; ++k) {
        short8 a0 = pa0[k & 3], a1 = pa1[k & 3];
        pa0[k & 3] = load_hfrag(hu + (size_t)(k + 4) * 8192);
        pa1[k & 3] = load_hfrag(hu + (size_t)(k + 4) * 8192 + 512);
        const us* wb = whu + (size_t)k * 4096;
        short8 b0 = ldf(wb);
        short8 b1 = ldf(wb + 1024);
        short8 b2 = ldf(wb + 2048);
        short8 b3 = ldf(wb + 3072);
        MFMA(acc[0][0], a0, b0); MFMA(acc[0][1], a0, b1);
        MFMA(acc[0][2], a0, b2); MFMA(acc[0][3], a0, b3);
        MFMA(acc[1][0], a1, b0); MFMA(acc[1][1], a1, b1);
        MFMA(acc[1][2], a1, b2); MFMA(acc[1][3], a1, b3);
      }
#pragma unroll 4
      for (int k = 16; k < 28; ++k) {
        short8 a0 = pa0[k & 3], a1 = pa1[k & 3];
        pa0[k & 3] = load_hfrag(hu + (size_t)(k + 4) * 8192);
        pa1[k & 3] = load_hfrag(hu + (size_t)(k + 4) * 8192 + 512);
        const unsigned char* lb = smem + (size_t)(k - 16) * 8192 + ldsofs;
        short8 b0 = *(const short8*)(lb);
        short8 b1 = *(const short8*)(lb + 2048);
        short8 b2 = *(const short8*)(lb + 4096);
        short8 b3 = *(const short8*)(lb + 6144);
        MFMA(acc[0][0], a0, b0); MFMA(acc[0][1], a0, b1);
        MFMA(acc[0][2], a0, b2); MFMA(acc[0][3], a0, b3);
        MFMA(acc[1][0], a1, b0); MFMA(acc[1][1], a1, b1);
        MFMA(acc[1][2], a1, b2); MFMA(acc[1][3], a1, b3);
      }
#pragma unroll
      for (int k = 28; k < 32; ++k) {
        short8 a0 = pa0[k & 3], a1 = pa1[k & 3];
        const unsigned char* lb = smem + (size_t)(k - 16) * 8192 + ldsofs;
        short8 b0 = *(const short8*)(lb);
        short8 b1 = *(const short8*)(lb + 2048);
        short8 b2 = *(const short8*)(lb + 4096);
        short8 b3 = *(const short8*)(lb + 6144);
        MFMA(acc[0][0], a0, b0); MFMA(acc[0][1], a0, b1);
        MFMA(acc[0][2], a0, b2); MFMA(acc[0][3], a0, b3);
        MFMA(acc[1][0], a1, b0); MFMA(acc[1][1], a1, b1);
        MFMA(acc[1][2], a1, b2); MFMA(acc[1][3], a1, b3);
      }
    }

    // ---- gate combine in registers; coherent h stores ----
    {
      const int q2 = nw * 2 + (c >> 3);
      const int e2 = c & 7;
      const size_t ob = ((size_t)(((p ^ 1) * 2 + dir) * 32 + jb) * 16 + bt0) * 512;
#pragma unroll
      for (int mt = 0; mt < 2; ++mt) {
        us* hd = Hf + ob + (size_t)mt * 512 + (size_t)(16 * q2) * 8 + e2;
#pragma unroll
        for (int rg = 0; rg < 4; ++rg) {
          float gi = acc[mt][0][rg], gf = acc[mt][1][rg];
          float go = acc[mt][2][rg], gc = acc[mt][3][rg];
          float cn = sigf(gf) * c_reg[mt][rg] + sigf(gi) * tanh_(gc);
          c_reg[mt][rg] = cn;
          __hip_atomic_store(hd + (size_t)(q * 4 + rg) * 8, f2bf(sigf(go) * tanh_(cn)),
                             __ATOMIC_RELAXED, __HIP_MEMORY_SCOPE_AGENT);
        }
      }
    }
    asm volatile("s_waitcnt vmcnt(0)" ::: "memory");
    __syncthreads();
    if (tid == 0)
      __hip_atomic_store(my_slot, (unsigned)(s + 1), __ATOMIC_RELAXED, __HIP_MEMORY_SCOPE_AGENT);
  }
}

// ---------------- Phase 4: logits + softmax, one block per batch row ----------------
__global__ void final_softmax(const us* __restrict__ Hf,  // buf 0
                              const float* __restrict__ Whq,
                              const float* __restrict__ bq,
                              float* __restrict__ out) {
  __shared__ float red[4][10];
  const int b = blockIdx.x;
  const int tid = threadIdx.x;
  float acc[10];
#pragma unroll
  for (int qq = 0; qq < 10; ++qq) acc[qq] = 0.f;
#pragma unroll
  for (int u = 0; u < 4; ++u) {
    int j = tid * 4 + u;
    int kt = j >> 5, q2 = (j & 31) >> 3, e = j & 7;
    size_t idx = (((size_t)kt * 16 + (b >> 4)) * 512) + ((size_t)((b & 15) + 16 * q2)) * 8 + e;
    float xv = bf2f(Hf[idx]) + bf2f(Hf[(size_t)32 * 16 * 512 + idx]);
#pragma unroll
    for (int qq = 0; qq < 10; ++qq) acc[qq] += xv * Whq[j * 10 + qq];
  }
#pragma unroll
  for (int qq = 0; qq < 10; ++qq)
#pragma unroll
    for (int off = 32; off; off >>= 1) acc[qq] += __shfl_down(acc[qq], off, 64);
  if ((tid & 63) == 0)
#pragma unroll
    for (int qq = 0; qq < 10; ++qq) red[tid >> 6][qq] = acc[qq];
  __syncthreads();
  if (tid == 0) {
    float t[10];
#pragma unroll
    for (int qq = 0; qq < 10; ++qq)
      t[qq] = red[0][qq] + red[1][qq] + red[2][qq] + red[3][qq] + bq[qq];
    float mx = t[0];
#pragma unroll
    for (int qq = 1; qq < 10; ++qq) mx = fmaxf(mx, t[qq]);
    float sum = 0.f;
#pragma unroll
    for (int qq = 0; qq < 10; ++qq) { t[qq] = __expf(t[qq] - mx); sum += t[qq]; }
    float inv = 1.0f / sum;
#pragma unroll
    for (int qq = 0; qq < 10; ++qq) out[b * 10 + qq] = t[qq] * inv;
  }
}

extern "C" void kernel_launch(void* const* d_in, const int* in_sizes, int n_in,
                              void* d_out, int out_size, void* d_ws, size_t ws_size,
                              hipStream_t stream) {
  const int*   inputs = (const int*)d_in[0];
  const float* emb    = (const float*)d_in[1];
  const float* Wx_f   = (const float*)d_in[2];
  const float* Wh_f   = (const float*)d_in[3];
  const float* b_f    = (const float*)d_in[4];
  const float* Wx_b   = (const float*)d_in[5];
  const float* Wh_b   = (const float*)d_in[6];
  const float* b_b    = (const float*)d_in[7];
  const float* W_hq   = (const float*)d_in[8];
  const float* b_q    = (const float*)d_in[9];
  float* out = (float*)d_out;

  char* ws = (char*)d_ws;
  us* Xf  = (us*)ws;                              // 64 MiB
  us* Wxp = (us*)(ws + (64ull << 20));            //  8 MiB
  us* Whp = (us*)(ws + (72ull << 20));            // 16 MiB
  us* Hf  = (us*)(ws + (88ull << 20));            //  2 MiB
  unsigned int* slt = (unsigned int*)(ws + (90ull << 20));  // 16 KiB

  hipMemsetAsync(Hf, 0, (size_t)2 * 2 * 32 * 16 * 512 * sizeof(us), stream);
  hipMemsetAsync(slt, 0, 8 * 32 * 16 * sizeof(unsigned int), stream);

  gather_embed<<<4096, 256, 0, stream>>>(inputs, emb, Xf);
  pack_w<<<6144, 256, 0, stream>>>(Wx_f, Wh_f, Wx_b, Wh_b, Wxp, Whp);

  hipFuncSetAttribute((const void*)lstm_main,
                      hipFuncAttributeMaxDynamicSharedMemorySize, LDS_BYTES);

  const us* xf_p = Xf;
  const us* wxp_p = Wxp;
  const us* whp_p = Whp;
  const float* bf_p = b_f;
  const float* bb_p = b_b;
  us* hf_p = Hf;
  unsigned int* slt_p = slt;
  void* kargs[] = { (void*)&xf_p, (void*)&wxp_p, (void*)&whp_p, (void*)&bf_p,
                    (void*)&bb_p, (void*)&hf_p, (void*)&slt_p };
  hipLaunchCooperativeKernel((void*)lstm_main, dim3(256), dim3(256), kargs, LDS_BYTES, stream);

  // final h (after step 256) lives in buf 0
  final_softmax<<<256, 256, 0, stream>>>(Hf, W_hq, b_q, out);
}